// Round 1
// baseline (186.951 us; speedup 1.0000x reference)
//
#include <hip/hip_runtime.h>
#include <hip/hip_bf16.h>
#include <string.h>

// ConvContract via bf16 MFMA implicit GEMM, pipelined + bank-conflict-free.
// prep:   Xb[y][c][col][cl] bf16, XOR-swizzled within each 8KB (y,c) row:
//         byte ^= ((col>>3)&7)<<4  (so conv's linear global_load_lds stage
//         yields a conflict-free LDS layout).  Also row sums -> partial.
// synth:  Fb[c][co][kpos] bf16, FS=192 (taps 9-11 zero), pre-swizzled:
//         short idx ^= (co&7)<<3.
// meanbx: meanb[c1] = b1 * sum_k F[64+c1][k] * meanX (torus identity).
// conv:   C[192][65536] = sum_c F*X, double-buffered LDS, ONE barrier per
//         channel (stage c+1 overlaps compute c), MFMA 16x16x32.

#define NN 256
#define NPIX 65536
#define OUT1_OFF 4194304
#define FS 192                 // F row stride (12 taps x 16 cl; taps 9-11 zero)
#define FBYT 36864             // 96 rows * FS * 2B per m-tile per channel
#define XBYT 24576             // 3 rows * 256 cols * 16 cl * 2B
#define BUFB 61440             // FBYT + XBYT = one pipeline buffer

typedef __attribute__((ext_vector_type(8))) short short8;
typedef __attribute__((ext_vector_type(4))) float floatx4;

__device__ __forceinline__ unsigned short f2b(float x) {
    unsigned int u; memcpy(&u, &x, 4);
    return (unsigned short)((u + 0x7FFFu + ((u >> 16) & 1u)) >> 16);   // RTNE
}
__device__ __forceinline__ float b2f16(unsigned short u) {
    unsigned int v = ((unsigned int)u) << 16; float f; memcpy(&f, &v, 4); return f;
}
__device__ __forceinline__ unsigned int pack2(float a, float b) {
    return (unsigned int)f2b(a) | ((unsigned int)f2b(b) << 16);
}

// ----------------------------------------------------------------- prep ----
// grid (64 ygroup, 12 c), block 256 = 4 waves (wave -> y), lane tx -> cols 4tx..4tx+3.
__global__ __launch_bounds__(256) void prep_kernel(const float* __restrict__ x0,
                                                   const float* __restrict__ x1,
                                                   unsigned short* __restrict__ Xb,
                                                   float* __restrict__ partial) {
    const int t = threadIdx.x;
    const int w = t >> 6, tx = t & 63;
    const int y = blockIdx.x * 4 + w;
    const int c = blockIdx.y;
    const int col0 = tx * 4;

    unsigned int u[4][8];
    float sum[16];
    if (c < 4) {
        #pragma unroll
        for (int j = 0; j < 8; j++) {
            const float4 a = *(const float4*)(x0 + (size_t)(16 * c + 2 * j) * NPIX + y * NN + col0);
            const float4 b = *(const float4*)(x0 + (size_t)(16 * c + 2 * j + 1) * NPIX + y * NN + col0);
            u[0][j] = pack2(a.x, b.x);
            u[1][j] = pack2(a.y, b.y);
            u[2][j] = pack2(a.z, b.z);
            u[3][j] = pack2(a.w, b.w);
            sum[2 * j]     = a.x + a.y + a.z + a.w;
            sum[2 * j + 1] = b.x + b.y + b.z + b.w;
        }
    } else {
        #pragma unroll
        for (int j = 0; j < 8; j++) {
            int i = 8 * (c - 4) + j;
            const float* base = x1 + ((size_t)(i * 256 + y) * 256 + col0) * 2;
            const float4 p0 = *(const float4*)(base);
            const float4 p1 = *(const float4*)(base + 4);
            u[0][j] = pack2(p0.x, p0.y);
            u[1][j] = pack2(p0.z, p0.w);
            u[2][j] = pack2(p1.x, p1.y);
            u[3][j] = pack2(p1.z, p1.w);
            sum[2 * j]     = p0.x + p0.z + p1.x + p1.z;
            sum[2 * j + 1] = p0.y + p0.w + p1.y + p1.w;
        }
    }
    // swizzled store: within the 8KB (y,c) row, byte ^= ((col>>3)&7)<<4
    char* rowp = (char*)(Xb + ((size_t)y * 12 + c) * 4096);
    #pragma unroll
    for (int cc = 0; cc < 4; cc++) {
        int col = col0 + cc;
        int sw = ((col >> 3) & 7) << 4;
        *(uint4*)(rowp + ((col * 32)      ^ sw)) = make_uint4(u[cc][0], u[cc][1], u[cc][2], u[cc][3]);
        *(uint4*)(rowp + ((col * 32 + 16) ^ sw)) = make_uint4(u[cc][4], u[cc][5], u[cc][6], u[cc][7]);
    }
    #pragma unroll
    for (int cl = 0; cl < 16; cl++)
        #pragma unroll
        for (int d = 1; d < 64; d <<= 1) sum[cl] += __shfl_xor(sum[cl], d, 64);
    if (tx < 16) partial[(c * 16 + tx) * 256 + y] = sum[tx];
}

// ---------------------------------------------------------------- synth ----
__global__ void synth_kernel(const float* __restrict__ fil0, const float* __restrict__ fil1,
                             const float* __restrict__ fil2,
                             const float* __restrict__ w00, const float* __restrict__ w01,
                             const float* __restrict__ w10, const float* __restrict__ w11,
                             unsigned short* __restrict__ Fb) {
    int idx = blockIdx.x * 256 + threadIdx.x;
    if (idx >= 12 * 192 * FS) return;
    int kpos = idx % FS;
    int co   = (idx / FS) % 192;
    int c    = idx / (FS * 192);
    int tap = kpos >> 4, cl = kpos & 15;
    float s = 0.0f;
    if (tap < 9) {
        int cin = c * 16 + cl;
        if (co < 64) {
            if (cin < 64) {
                for (int k = 0; k < 3; k++)
                    s += w00[(co * 64 + cin) * 3 + k] * fil0[k * 9 + tap];
            } else {
                int i = (cin - 64) >> 1, t = (cin - 64) & 1;
                for (int k = 0; k < 6; k++)
                    s += w10[(co * 64 + i) * 6 + k] * fil1[(k * 9 + tap) * 2 + t];
            }
        } else {
            int o = (co - 64) >> 1, u = (co - 64) & 1;
            if (cin < 64) {
                for (int k = 0; k < 6; k++)
                    s += w01[(o * 64 + cin) * 6 + k] * fil1[(k * 9 + tap) * 2 + u];
            } else {
                int i = (cin - 64) >> 1, t = (cin - 64) & 1;
                for (int k = 0; k < 12; k++)
                    s += w11[(o * 64 + i) * 12 + k] * fil2[((k * 9 + tap) * 2 + t) * 2 + u];
            }
        }
    }
    // pre-swizzled (matches conv's A-read XOR of byte bits 4-6 with (row&7)<<4)
    Fb[((size_t)c * 192 + co) * FS + (kpos ^ ((co & 7) << 3))] = f2b(s);
}

// --------------------------------------------------------------- meanbx ----
// grid 128 (c1), block 256. Each block recomputes meanX (L2-resident partial).
__global__ void meanbx_kernel(const unsigned short* __restrict__ Fb,
                              const float* __restrict__ partial,
                              const float* __restrict__ b1, float* __restrict__ meanb) {
    __shared__ float mX[192];
    __shared__ float rd[4];
    const int c1 = blockIdx.x;
    const int t = threadIdx.x;
    if (t < 192) {
        const float4* p = (const float4*)(partial + (size_t)t * 256);
        float s = 0.0f;
        for (int j = 0; j < 64; j++) { float4 v = p[j]; s += v.x + v.y + v.z + v.w; }
        mX[t] = s * (1.0f / 65536.0f);
    }
    __syncthreads();
    float s = 0.0f;
    for (int e = t; e < 1728; e += 256) {
        int c = e / 144, r = e - c * 144;
        int tap = r >> 4, cl = r & 15;
        s += b2f16(Fb[((size_t)c * 192 + 64 + c1) * FS + ((tap * 16 + cl) ^ ((c1 & 7) << 3))])
             * mX[c * 16 + cl];
    }
#pragma unroll
    for (int d = 1; d < 64; d <<= 1) s += __shfl_xor(s, d, 64);
    if ((t & 63) == 0) rd[t >> 6] = s;
    __syncthreads();
    if (t == 0) meanb[c1] = (rd[0] + rd[1] + rd[2] + rd[3]) * b1[c1 >> 1];
}

// ----------------------------------------------------------------- conv ----
// grid (256 y, 2 mtile), block 512 = 8 waves (2 wm x 4 wn); wave tile 48M x 64N.
// Double-buffered LDS, one barrier per channel: stage(c+1) issued before
// compute(c); __syncthreads() (vmcnt0+barrier) drains after compute hides it.
__global__ __launch_bounds__(512, 2) void conv_kernel(
    const unsigned short* __restrict__ Xb, const unsigned short* __restrict__ Fb,
    const float* __restrict__ b0, const float* __restrict__ meanb,
    float* __restrict__ out) {

    __shared__ __align__(16) char lds[2 * BUFB];      // 122880 B -> 1 block/CU

    const int tid = threadIdx.x;
    const int y = blockIdx.x;
    const int m0 = blockIdx.y * 96;
    const int l = tid & 63, w = tid >> 6;
    const int wm = w >> 2, wn = w & 3;
    const int mw = wm * 48, nw = wn * 64;
    const int ln = l & 15, quad = l >> 4;

    // ---- precompute all swizzled LDS read offsets (c-invariant) ----
    int addrA[5][3];
    int addrB[5][4];
    const int swzA = (ln & 7) << 4;
#pragma unroll
    for (int ks = 0; ks < 5; ks++) {
#pragma unroll
        for (int f = 0; f < 3; f++) {
            int row = mw + f * 16 + ln;                 // row&7 == ln&7
            addrA[ks][f] = (row * (FS * 2) + quad * 16 + ks * 64) ^ swzA;
        }
        int tap = 2 * ks + (quad >> 1);
        int r, dx;
        if (tap > 8) { r = 0; dx = 0; }                 // zero-pad tap: F=0
        else { r = tap / 3; dx = tap - 3 * r - 1; }
#pragma unroll
        for (int g = 0; g < 4; g++) {
            int colw = (nw + g * 16 + ln + dx) & 255;
            addrB[ks][g] = FBYT + r * 8192 +
                ((colw * 32 + (quad & 1) * 16) ^ (((colw >> 3) & 7) << 4));
        }
    }

    floatx4 acc[3][4];
#pragma unroll
    for (int f = 0; f < 3; f++)
#pragma unroll
        for (int g = 0; g < 4; g++) acc[f][g] = (floatx4){0.f, 0.f, 0.f, 0.f};

    // ---- async stage of one channel into buffer bsel (60 segs x 1KB) ----
    auto stage = [&](int c, int bsel) {
        const unsigned short* FbC = Fb + ((size_t)c * 192 + m0) * FS;
        char* base = lds + bsel * BUFB;
        for (int s = w; s < 60; s += 8) {
            const unsigned short* g;
            char* lb;
            if (s < 36) {                                // F: 36864 B linear
                g = FbC + s * 512;
                lb = base + s * 1024;
            } else {                                     // X: 3 rows x 8192 B
                int j = s - 36;
                int r = j >> 3, p = j & 7;
                int yr = (y + r + 255) & 255;
                g = Xb + ((size_t)yr * 12 + c) * 4096 + p * 512;
                lb = base + FBYT + r * 8192 + p * 1024;
            }
            __builtin_amdgcn_global_load_lds(
                (const __attribute__((address_space(1))) unsigned int*)(g + l * 8),
                (__attribute__((address_space(3))) unsigned int*)lb, 16, 0, 0);
        }
    };

    stage(0, 0);
    __syncthreads();

    int cur = 0;
    for (int c = 0; c < 12; c++) {
        if (c < 11) stage(c + 1, cur ^ 1);               // overlaps compute below
        const char* fb = lds + cur * BUFB;
#pragma unroll
        for (int ks = 0; ks < 5; ks++) {
            short8 A[3], B[4];
#pragma unroll
            for (int f = 0; f < 3; f++) A[f] = *(const short8*)(fb + addrA[ks][f]);
#pragma unroll
            for (int g = 0; g < 4; g++) B[g] = *(const short8*)(fb + addrB[ks][g]);
#pragma unroll
            for (int f = 0; f < 3; f++)
#pragma unroll
                for (int g = 0; g < 4; g++)
                    acc[f][g] = __builtin_amdgcn_mfma_f32_16x16x32_bf16(A[f], B[g], acc[f][g], 0, 0, 0);
        }
        __syncthreads();                                  // drains stage(c+1)
        cur ^= 1;
    }

    // ------------------------------------------------------- epilogue ----
    // C/D layout: col = ln, row(within 16) = quad*4 + reg.
#pragma unroll
    for (int f = 0; f < 3; f++) {
        int cob = m0 + mw + f * 16 + quad * 4;
#pragma unroll
        for (int g = 0; g < 4; g++) {
            int col = nw + g * 16 + ln;
            if (cob < 64) {
#pragma unroll
                for (int reg = 0; reg < 4; reg++)
                    out[(size_t)(cob + reg) * NPIX + y * NN + col] = acc[f][g][reg] + b0[cob + reg];
            } else {
#pragma unroll
                for (int reg = 0; reg < 4; reg += 2) {
                    int c1 = cob + reg - 64;
                    int o = c1 >> 1;
                    float2 v = make_float2(acc[f][g][reg] + meanb[c1],
                                           acc[f][g][reg + 1] + meanb[c1 + 1]);
                    *((float2*)(out + OUT1_OFF) + ((size_t)o * NPIX + y * NN + col)) = v;
                }
            }
        }
    }
}

// --------------------------------------------------------------- launch ----
extern "C" void kernel_launch(void* const* d_in, const int* in_sizes, int n_in,
                              void* d_out, int out_size, void* d_ws, size_t ws_size,
                              hipStream_t stream) {
    const float* x0   = (const float*)d_in[0];
    const float* x1   = (const float*)d_in[1];
    const float* fil0 = (const float*)d_in[2];
    const float* fil1 = (const float*)d_in[3];
    const float* fil2 = (const float*)d_in[4];
    const float* w00  = (const float*)d_in[5];
    const float* w01  = (const float*)d_in[6];
    const float* w10  = (const float*)d_in[7];
    const float* w11  = (const float*)d_in[8];
    const float* b0   = (const float*)d_in[9];
    const float* b1   = (const float*)d_in[10];

    unsigned short* Xb = (unsigned short*)d_ws;                       // 25,165,824 B
    unsigned short* Fb = (unsigned short*)((char*)d_ws + 25165824);   //    884,736 B
    float* partial     = (float*)((char*)d_ws + 26050560);            //    196,608 B
    float* meanb       = (float*)((char*)d_ws + 26247168);            //        512 B
    float* out = (float*)d_out;

    prep_kernel<<<dim3(64, 12), 256, 0, stream>>>(x0, x1, Xb, partial);

    synth_kernel<<<(12 * 192 * FS + 255) / 256, 256, 0, stream>>>(
        fil0, fil1, fil2, w00, w01, w10, w11, Fb);

    meanbx_kernel<<<128, 256, 0, stream>>>(Fb, partial, b1, meanb);

    conv_kernel<<<dim3(NN, 2), 512, 0, stream>>>(Xb, Fb, b0, meanb, out);
}

// Round 2
// 184.060 us; speedup vs baseline: 1.0157x; 1.0157x over previous
//
#include <hip/hip_runtime.h>
#include <hip/hip_bf16.h>
#include <string.h>

// ConvContract via bf16 MFMA implicit GEMM.
// prep:   Xb[y][c][col][cl] bf16, XOR-swizzled within each 8KB (y,c) row:
//         byte ^= ((col>>3)&7)<<4  (conv's linear global_load_lds stage then
//         yields a bank-clean LDS layout).  Row sums -> partial.
//         y-groups XCD-chunked to match conv's reader XCD.
// synth:  Fg[c][rt][ks][lane][8] bf16 (coalesced A-fragment layout): lane
//         l=quad*16+ln of a wave reads its 16B fragment at base+16*l.
//         co = rt*16+ln, kpos = ks*32+quad*8+j (tap 9 zero).
// meanbx: meanb[c1] = b1 * sum_k F[64+c1][k] * meanX (torus identity).
// conv:   C[192][65536] = sum_c F*X. F: direct global->reg loads (L1/L2
//         resident, no LDS). X: double-buffered LDS via global_load_lds,
//         stage(c+1) overlaps compute(c), ONE barrier per channel.

#define NN 256
#define NPIX 65536
#define OUT1_OFF 4194304
#define XB_CH 4096        // shorts per (y,c) row: 256 cols * 16 cl
#define FG_C 30720        // shorts per channel of Fg: 12 rt * 5 ks * 512
#define XTILE 24576       // bytes per X LDS buffer: 3 rows * 8192

typedef __attribute__((ext_vector_type(8))) short short8;
typedef __attribute__((ext_vector_type(4))) float floatx4;

__device__ __forceinline__ unsigned short f2b(float x) {
    unsigned int u; memcpy(&u, &x, 4);
    return (unsigned short)((u + 0x7FFFu + ((u >> 16) & 1u)) >> 16);   // RTNE
}
__device__ __forceinline__ float b2f16(unsigned short u) {
    unsigned int v = ((unsigned int)u) << 16; float f; memcpy(&f, &v, 4); return f;
}
__device__ __forceinline__ unsigned int pack2(float a, float b) {
    return (unsigned int)f2b(a) | ((unsigned int)f2b(b) << 16);
}

// ----------------------------------------------------------------- prep ----
// grid (64 ygroup, 12 c), block 256 = 4 waves (wave -> y), lane tx -> cols 4tx..4tx+3.
// ygroup XCD-chunked: XCD k handles y in [32k, 32k+32) — matches conv.
__global__ __launch_bounds__(256) void prep_kernel(const float* __restrict__ x0,
                                                   const float* __restrict__ x1,
                                                   unsigned short* __restrict__ Xb,
                                                   float* __restrict__ partial) {
    const int t = threadIdx.x;
    const int w = t >> 6, tx = t & 63;
    const int bxs = blockIdx.x;
    const int yg = ((bxs & 7) << 3) | (bxs >> 3);     // XCD-chunked ygroup
    const int y = yg * 4 + w;
    const int c = blockIdx.y;
    const int col0 = tx * 4;

    unsigned int u[4][8];
    float sum[16];
    if (c < 4) {
        #pragma unroll
        for (int j = 0; j < 8; j++) {
            const float4 a = *(const float4*)(x0 + (size_t)(16 * c + 2 * j) * NPIX + y * NN + col0);
            const float4 b = *(const float4*)(x0 + (size_t)(16 * c + 2 * j + 1) * NPIX + y * NN + col0);
            u[0][j] = pack2(a.x, b.x);
            u[1][j] = pack2(a.y, b.y);
            u[2][j] = pack2(a.z, b.z);
            u[3][j] = pack2(a.w, b.w);
            sum[2 * j]     = a.x + a.y + a.z + a.w;
            sum[2 * j + 1] = b.x + b.y + b.z + b.w;
        }
    } else {
        #pragma unroll
        for (int j = 0; j < 8; j++) {
            int i = 8 * (c - 4) + j;
            const float* base = x1 + ((size_t)(i * 256 + y) * 256 + col0) * 2;
            const float4 p0 = *(const float4*)(base);
            const float4 p1 = *(const float4*)(base + 4);
            u[0][j] = pack2(p0.x, p0.y);
            u[1][j] = pack2(p0.z, p0.w);
            u[2][j] = pack2(p1.x, p1.y);
            u[3][j] = pack2(p1.z, p1.w);
            sum[2 * j]     = p0.x + p0.z + p1.x + p1.z;
            sum[2 * j + 1] = p0.y + p0.w + p1.y + p1.w;
        }
    }
    // swizzled store: within the 8KB (y,c) row, byte ^= ((col>>3)&7)<<4
    char* rowp = (char*)(Xb + ((size_t)y * 12 + c) * XB_CH);
    #pragma unroll
    for (int cc = 0; cc < 4; cc++) {
        int col = col0 + cc;
        int sw = ((col >> 3) & 7) << 4;
        *(uint4*)(rowp + ((col * 32)      ^ sw)) = make_uint4(u[cc][0], u[cc][1], u[cc][2], u[cc][3]);
        *(uint4*)(rowp + ((col * 32 + 16) ^ sw)) = make_uint4(u[cc][4], u[cc][5], u[cc][6], u[cc][7]);
    }
    #pragma unroll
    for (int cl = 0; cl < 16; cl++)
        #pragma unroll
        for (int d = 1; d < 64; d <<= 1) sum[cl] += __shfl_xor(sum[cl], d, 64);
    if (tx < 16) partial[(c * 16 + tx) * 256 + y] = sum[tx];
}

// ---------------------------------------------------------------- synth ----
// Fg element idx = ((c*12 + rt)*5 + ks)*512 + lane*8 + j, lane = quad*16+ln.
__global__ void synth_kernel(const float* __restrict__ fil0, const float* __restrict__ fil1,
                             const float* __restrict__ fil2,
                             const float* __restrict__ w00, const float* __restrict__ w01,
                             const float* __restrict__ w10, const float* __restrict__ w11,
                             unsigned short* __restrict__ Fg) {
    int idx = blockIdx.x * 256 + threadIdx.x;
    if (idx >= 12 * 12 * 5 * 512) return;
    int sub = idx & 511;
    int blk = idx >> 9;
    int ks = blk % 5;
    int rc = blk / 5;
    int rt = rc % 12;
    int c = rc / 12;
    int lane = sub >> 3, j = sub & 7;
    int quad = lane >> 4, ln = lane & 15;
    int co = rt * 16 + ln;
    int kpos = ks * 32 + quad * 8 + j;
    int tap = kpos >> 4, cl = kpos & 15;
    float s = 0.0f;
    if (tap < 9) {
        int cin = c * 16 + cl;
        if (co < 64) {
            if (cin < 64) {
                for (int k = 0; k < 3; k++)
                    s += w00[(co * 64 + cin) * 3 + k] * fil0[k * 9 + tap];
            } else {
                int i = (cin - 64) >> 1, t = (cin - 64) & 1;
                for (int k = 0; k < 6; k++)
                    s += w10[(co * 64 + i) * 6 + k] * fil1[(k * 9 + tap) * 2 + t];
            }
        } else {
            int o = (co - 64) >> 1, u = (co - 64) & 1;
            if (cin < 64) {
                for (int k = 0; k < 6; k++)
                    s += w01[(o * 64 + cin) * 6 + k] * fil1[(k * 9 + tap) * 2 + u];
            } else {
                int i = (cin - 64) >> 1, t = (cin - 64) & 1;
                for (int k = 0; k < 12; k++)
                    s += w11[(o * 64 + i) * 12 + k] * fil2[((k * 9 + tap) * 2 + t) * 2 + u];
            }
        }
    }
    Fg[idx] = f2b(s);
}

// --------------------------------------------------------------- meanbx ----
// grid 128 (c1), block 256. Each block recomputes meanX (L2-resident partial).
__global__ void meanbx_kernel(const unsigned short* __restrict__ Fg,
                              const float* __restrict__ partial,
                              const float* __restrict__ b1, float* __restrict__ meanb) {
    __shared__ float mX[192];
    __shared__ float rd[4];
    const int c1 = blockIdx.x;
    const int t = threadIdx.x;
    if (t < 192) {
        const float4* p = (const float4*)(partial + (size_t)t * 256);
        float s = 0.0f;
        for (int j = 0; j < 64; j++) { float4 v = p[j]; s += v.x + v.y + v.z + v.w; }
        mX[t] = s * (1.0f / 65536.0f);
    }
    __syncthreads();
    float s = 0.0f;
    for (int e = t; e < 1728; e += 256) {
        int c = e / 144, r = e - c * 144;                  // r = kpos in [0,144)
        int cl = r & 15;
        int fidx = ((c * 12 + 4 + (c1 >> 4)) * 5 + (r >> 5)) * 512
                 + ((((r >> 3) & 3) * 16 + (c1 & 15)) << 3) + (r & 7);
        s += b2f16(Fg[fidx]) * mX[c * 16 + cl];
    }
#pragma unroll
    for (int d = 1; d < 64; d <<= 1) s += __shfl_xor(s, d, 64);
    if ((t & 63) == 0) rd[t >> 6] = s;
    __syncthreads();
    if (t == 0) meanb[c1] = (rd[0] + rd[1] + rd[2] + rd[3]) * b1[c1 >> 1];
}

// ----------------------------------------------------------------- conv ----
// grid (256 y, 2 mtile), block 512 = 8 waves (2 wm x 4 wn); wave tile 48M x 64N.
// F: global->reg coalesced loads (no LDS). X: dbuf LDS, stage(c+1) || compute(c).
__global__ __launch_bounds__(512, 4) void conv_kernel(
    const unsigned short* __restrict__ Xb, const unsigned short* __restrict__ Fg,
    const float* __restrict__ b0, const float* __restrict__ meanb,
    float* __restrict__ out) {

    __shared__ __align__(16) char lds[2 * XTILE];         // 49152 B -> 2 blocks/CU

    const int tid = threadIdx.x;
    const int bx = blockIdx.x;
    const int y = ((bx & 7) << 5) | (bx >> 3);            // XCD-chunked y
    const int m0 = blockIdx.y * 96;
    const int l = tid & 63, w = tid >> 6;
    const int wm = w >> 2, wn = w & 3;
    const int nw = wn * 64;
    const int ln = l & 15, quad = l >> 4;

    // ---- A: per-lane global base pointers (coalesced 16B/lane) ----
    const unsigned short* pF[3];
#pragma unroll
    for (int f = 0; f < 3; f++) {
        int rt = blockIdx.y * 6 + wm * 3 + f;
        pF[f] = Fg + ((size_t)rt * 320 + l) * 8;          // + c*FG_C + ks*512
    }

    // ---- B: swizzled LDS read offsets (c-invariant, relative to buffer) ----
    int addrB[5][4];
#pragma unroll
    for (int ks = 0; ks < 5; ks++) {
        int tap = 2 * ks + (quad >> 1);
        int r, dx;
        if (tap > 8) { r = 0; dx = 0; }                   // zero-pad tap: F=0
        else { r = tap / 3; dx = tap - 3 * r - 1; }
#pragma unroll
        for (int g = 0; g < 4; g++) {
            int colw = (nw + g * 16 + ln + dx) & 255;
            addrB[ks][g] = r * 8192 +
                ((colw * 32 + (quad & 1) * 16) ^ (((colw >> 3) & 7) << 4));
        }
    }

    floatx4 acc[3][4];
#pragma unroll
    for (int f = 0; f < 3; f++)
#pragma unroll
        for (int g = 0; g < 4; g++) acc[f][g] = (floatx4){0.f, 0.f, 0.f, 0.f};

    // ---- async stage of one channel's X into buffer bsel (24 x 1KB) ----
    auto stage = [&](int c, int bsel) {
        char* base = lds + bsel * XTILE;
#pragma unroll
        for (int i = 0; i < 3; i++) {
            int yr = (y + i + 255) & 255;
            const unsigned short* g = Xb + ((size_t)yr * 12 + c) * XB_CH + w * 512;
            __builtin_amdgcn_global_load_lds(
                (const __attribute__((address_space(1))) unsigned int*)(g + l * 8),
                (__attribute__((address_space(3))) unsigned int*)(base + i * 8192 + w * 1024),
                16, 0, 0);
        }
    };

    stage(0, 0);
    __syncthreads();

    int cur = 0;
    size_t coff = 0;
    for (int c = 0; c < 12; c++) {
        if (c < 11) stage(c + 1, cur ^ 1);                // overlaps compute below
        const char* xb = lds + cur * XTILE;
#pragma unroll
        for (int ks = 0; ks < 5; ks++) {
            short8 A[3], B[4];
#pragma unroll
            for (int f = 0; f < 3; f++)
                A[f] = *(const short8*)(pF[f] + coff + ks * 512);
#pragma unroll
            for (int g = 0; g < 4; g++)
                B[g] = *(const short8*)(xb + addrB[ks][g]);
#pragma unroll
            for (int f = 0; f < 3; f++)
#pragma unroll
                for (int g = 0; g < 4; g++)
                    acc[f][g] = __builtin_amdgcn_mfma_f32_16x16x32_bf16(A[f], B[g], acc[f][g], 0, 0, 0);
        }
        coff += FG_C;
        __syncthreads();                                  // drains stage(c+1)
        cur ^= 1;
    }

    // ------------------------------------------------------- epilogue ----
    // C/D layout: col = ln, row(within 16) = quad*4 + reg.
    const int mw = wm * 48;
#pragma unroll
    for (int f = 0; f < 3; f++) {
        int cob = m0 + mw + f * 16 + quad * 4;
#pragma unroll
        for (int g = 0; g < 4; g++) {
            int col = nw + g * 16 + ln;
            if (cob < 64) {
#pragma unroll
                for (int reg = 0; reg < 4; reg++)
                    out[(size_t)(cob + reg) * NPIX + y * NN + col] = acc[f][g][reg] + b0[cob + reg];
            } else {
#pragma unroll
                for (int reg = 0; reg < 4; reg += 2) {
                    int c1 = cob + reg - 64;
                    int o = c1 >> 1;
                    float2 v = make_float2(acc[f][g][reg] + meanb[c1],
                                           acc[f][g][reg + 1] + meanb[c1 + 1]);
                    *((float2*)(out + OUT1_OFF) + ((size_t)o * NPIX + y * NN + col)) = v;
                }
            }
        }
    }
}

// --------------------------------------------------------------- launch ----
extern "C" void kernel_launch(void* const* d_in, const int* in_sizes, int n_in,
                              void* d_out, int out_size, void* d_ws, size_t ws_size,
                              hipStream_t stream) {
    const float* x0   = (const float*)d_in[0];
    const float* x1   = (const float*)d_in[1];
    const float* fil0 = (const float*)d_in[2];
    const float* fil1 = (const float*)d_in[3];
    const float* fil2 = (const float*)d_in[4];
    const float* w00  = (const float*)d_in[5];
    const float* w01  = (const float*)d_in[6];
    const float* w10  = (const float*)d_in[7];
    const float* w11  = (const float*)d_in[8];
    const float* b0   = (const float*)d_in[9];
    const float* b1   = (const float*)d_in[10];

    unsigned short* Xb = (unsigned short*)d_ws;                       // 25,165,824 B
    unsigned short* Fg = (unsigned short*)((char*)d_ws + 25165824);   //    737,280 B
    float* partial     = (float*)((char*)d_ws + 25903104);            //    196,608 B
    float* meanb       = (float*)((char*)d_ws + 26099712);            //        512 B
    float* out = (float*)d_out;

    prep_kernel<<<dim3(64, 12), 256, 0, stream>>>(x0, x1, Xb, partial);

    synth_kernel<<<(12 * 12 * 5 * 512 + 255) / 256, 256, 0, stream>>>(
        fil0, fil1, fil2, w00, w01, w10, w11, Fg);

    meanbx_kernel<<<128, 256, 0, stream>>>(Fg, partial, b1, meanb);

    conv_kernel<<<dim3(NN, 2), 512, 0, stream>>>(Xb, Fg, b0, meanb, out);
}

// Round 4
// 174.263 us; speedup vs baseline: 1.0728x; 1.0562x over previous
//
#include <hip/hip_runtime.h>
#include <hip/hip_bf16.h>
#include <string.h>

// ConvContract via bf16 MFMA implicit GEMM, 32x32x16 edition.
// prep:   Xb[y][c][col][cl] bf16, XOR-swizzled within each 8KB (y,c) row:
//         byte ^= (col&7)<<4  (conv stages linearly; reads use same XOR ->
//         bank-conflict-free ds_read_b128, verified per-lane granule map).
// synth:  Fg[c][co][144] bf16 (9 taps x 16 cl), pre-swizzled per 8-granule
//         aligned block: taps 0-7: g ^= co&7; tap 8 (granules 16,17):
//         g ^= (co>>2)&1  (XOR must stay closed within the 144-short row).
// meanbx: meanb[c1] = b1 * sum_k F[64+c1][k] * meanX (torus identity).
// conv:   C[192][65536] = sum_c F*X via mfma_f32_32x32x16_bf16 (2x FLOP per
//         LDS byte vs 16x16x32; K-step = one tap, no zero-pad taps).
//         grid 256 (1 block/CU), 8 waves, wave tile 96x64.
//         F+X double-buffered LDS (159744 B), stage(c+1) || compute(c),
//         ONE barrier per channel.

#define NN 256
#define NPIX 65536
#define OUT1_OFF 4194304
#define XB_CH 4096        // shorts per (y,c) row: 256 cols * 16 cl
#define FG_C 27648        // shorts per channel of Fg: 192 rows * 144
#define FBYT 55296        // bytes of F per channel in LDS
#define XOFF 55296        // X offset within buffer
#define BUFB 79872        // FBYT + 24576

typedef __attribute__((ext_vector_type(8))) short short8;
typedef __attribute__((ext_vector_type(16))) float floatx16;

__device__ __forceinline__ unsigned short f2b(float x) {
    unsigned int u; memcpy(&u, &x, 4);
    return (unsigned short)((u + 0x7FFFu + ((u >> 16) & 1u)) >> 16);   // RTNE
}
__device__ __forceinline__ float b2f16(unsigned short u) {
    unsigned int v = ((unsigned int)u) << 16; float f; memcpy(&f, &v, 4); return f;
}
__device__ __forceinline__ unsigned int pack2(float a, float b) {
    return (unsigned int)f2b(a) | ((unsigned int)f2b(b) << 16);
}

// ----------------------------------------------------------------- prep ----
// grid (64 ygroup, 12 c), block 256 = 4 waves (wave -> y), lane tx -> cols 4tx..4tx+3.
// ygroup XCD-chunked: XCD k handles y in [32k, 32k+32) — matches conv.
__global__ __launch_bounds__(256) void prep_kernel(const float* __restrict__ x0,
                                                   const float* __restrict__ x1,
                                                   unsigned short* __restrict__ Xb,
                                                   float* __restrict__ partial) {
    const int t = threadIdx.x;
    const int w = t >> 6, tx = t & 63;
    const int bxs = blockIdx.x;
    const int yg = ((bxs & 7) << 3) | (bxs >> 3);     // XCD-chunked ygroup
    const int y = yg * 4 + w;
    const int c = blockIdx.y;
    const int col0 = tx * 4;

    unsigned int u[4][8];
    float sum[16];
    if (c < 4) {
        #pragma unroll
        for (int j = 0; j < 8; j++) {
            const float4 a = *(const float4*)(x0 + (size_t)(16 * c + 2 * j) * NPIX + y * NN + col0);
            const float4 b = *(const float4*)(x0 + (size_t)(16 * c + 2 * j + 1) * NPIX + y * NN + col0);
            u[0][j] = pack2(a.x, b.x);
            u[1][j] = pack2(a.y, b.y);
            u[2][j] = pack2(a.z, b.z);
            u[3][j] = pack2(a.w, b.w);
            sum[2 * j]     = a.x + a.y + a.z + a.w;
            sum[2 * j + 1] = b.x + b.y + b.z + b.w;
        }
    } else {
        #pragma unroll
        for (int j = 0; j < 8; j++) {
            int i = 8 * (c - 4) + j;
            const float* base = x1 + ((size_t)(i * 256 + y) * 256 + col0) * 2;
            const float4 p0 = *(const float4*)(base);
            const float4 p1 = *(const float4*)(base + 4);
            u[0][j] = pack2(p0.x, p0.y);
            u[1][j] = pack2(p0.z, p0.w);
            u[2][j] = pack2(p1.x, p1.y);
            u[3][j] = pack2(p1.z, p1.w);
            sum[2 * j]     = p0.x + p0.z + p1.x + p1.z;
            sum[2 * j + 1] = p0.y + p0.w + p1.y + p1.w;
        }
    }
    // swizzled store: within the 8KB (y,c) row, byte ^= (col&7)<<4
    char* rowp = (char*)(Xb + ((size_t)y * 12 + c) * XB_CH);
    #pragma unroll
    for (int cc = 0; cc < 4; cc++) {
        int col = col0 + cc;
        int sw = (col & 7) << 4;
        *(uint4*)(rowp + ((col * 32)      ^ sw)) = make_uint4(u[cc][0], u[cc][1], u[cc][2], u[cc][3]);
        *(uint4*)(rowp + ((col * 32 + 16) ^ sw)) = make_uint4(u[cc][4], u[cc][5], u[cc][6], u[cc][7]);
    }
    #pragma unroll
    for (int cl = 0; cl < 16; cl++)
        #pragma unroll
        for (int d = 1; d < 64; d <<= 1) sum[cl] += __shfl_xor(sum[cl], d, 64);
    if (tx < 16) partial[(c * 16 + tx) * 256 + y] = sum[tx];
}

// ---------------------------------------------------------------- synth ----
// Fg[c][co][off_sw]: taps 0-7: off = ((tap*16+(cl&8)) ^ ((co&7)<<3)) + (cl&7);
// tap 8: off = ((128+(cl&8)) ^ (((co>>2)&1)<<3)) + (cl&7)  (closure-safe).
__global__ void synth_kernel(const float* __restrict__ fil0, const float* __restrict__ fil1,
                             const float* __restrict__ fil2,
                             const float* __restrict__ w00, const float* __restrict__ w01,
                             const float* __restrict__ w10, const float* __restrict__ w11,
                             unsigned short* __restrict__ Fg) {
    int idx = blockIdx.x * 256 + threadIdx.x;
    if (idx >= 12 * 192 * 144) return;
    int kpos = idx % 144;
    int co   = (idx / 144) % 192;
    int c    = idx / (144 * 192);
    int tap = kpos >> 4, cl = kpos & 15;
    float s = 0.0f;
    {
        int cin = c * 16 + cl;
        if (co < 64) {
            if (cin < 64) {
                for (int k = 0; k < 3; k++)
                    s += w00[(co * 64 + cin) * 3 + k] * fil0[k * 9 + tap];
            } else {
                int i = (cin - 64) >> 1, t = (cin - 64) & 1;
                for (int k = 0; k < 6; k++)
                    s += w10[(co * 64 + i) * 6 + k] * fil1[(k * 9 + tap) * 2 + t];
            }
        } else {
            int o = (co - 64) >> 1, u = (co - 64) & 1;
            if (cin < 64) {
                for (int k = 0; k < 6; k++)
                    s += w01[(o * 64 + cin) * 6 + k] * fil1[(k * 9 + tap) * 2 + u];
            } else {
                int i = (cin - 64) >> 1, t = (cin - 64) & 1;
                for (int k = 0; k < 12; k++)
                    s += w11[(o * 64 + i) * 12 + k] * fil2[((k * 9 + tap) * 2 + t) * 2 + u];
            }
        }
    }
    int swz = (tap < 8) ? ((co & 7) << 3) : (((co >> 2) & 1) << 3);
    int off = ((tap * 16 + (cl & 8)) ^ swz) + (cl & 7);
    Fg[((size_t)c * 192 + co) * 144 + off] = f2b(s);
}

// --------------------------------------------------------------- meanbx ----
// grid 128 (c1), block 256. Each block recomputes meanX (L2-resident partial).
__global__ void meanbx_kernel(const unsigned short* __restrict__ Fg,
                              const float* __restrict__ partial,
                              const float* __restrict__ b1, float* __restrict__ meanb) {
    __shared__ float mX[192];
    __shared__ float rd[4];
    const int c1 = blockIdx.x;
    const int t = threadIdx.x;
    if (t < 192) {
        const float4* p = (const float4*)(partial + (size_t)t * 256);
        float s = 0.0f;
        for (int j = 0; j < 64; j++) { float4 v = p[j]; s += v.x + v.y + v.z + v.w; }
        mX[t] = s * (1.0f / 65536.0f);
    }
    __syncthreads();
    float s = 0.0f;
    for (int e = t; e < 1728; e += 256) {
        int c = e / 144, r = e - c * 144;
        int tap = r >> 4, cl = r & 15;
        int swz = (tap < 8) ? ((c1 & 7) << 3) : (((c1 >> 2) & 1) << 3);
        int off = ((tap * 16 + (cl & 8)) ^ swz) + (cl & 7);
        s += b2f16(Fg[((size_t)c * 192 + 64 + c1) * 144 + off]) * mX[c * 16 + cl];
    }
#pragma unroll
    for (int d = 1; d < 64; d <<= 1) s += __shfl_xor(s, d, 64);
    if ((t & 63) == 0) rd[t >> 6] = s;
    __syncthreads();
    if (t == 0) meanb[c1] = (rd[0] + rd[1] + rd[2] + rd[3]) * b1[c1 >> 1];
}

// ----------------------------------------------------------------- conv ----
// grid 256 (y), block 512 = 8 waves (2 wm x 4 wn); wave tile 96M x 64N.
// mfma_f32_32x32x16_bf16: per tap, A 3 frags (96 rows), B 2 frags (64 cols),
// 6 MFMA. A/B lane map: row/col = lane&31, k = (lane>>5)*8 + j (consistent
// on both operands). C/D: col = lane&31, row = (reg&3)+8*(reg>>2)+4*(lane>>5).
__global__ __launch_bounds__(512, 2) void conv_kernel(
    const unsigned short* __restrict__ Xb, const unsigned short* __restrict__ Fg,
    const float* __restrict__ b0, const float* __restrict__ meanb,
    float* __restrict__ out) {

    __shared__ __align__(16) char lds[2 * BUFB];          // 159744 B

    const int tid = threadIdx.x;
    const int bx = blockIdx.x;
    const int y = ((bx & 7) << 5) | (bx >> 3);            // XCD-chunked y
    const int l = tid & 63, w = tid >> 6;
    const int wm = w >> 2, wn = w & 3;
    const int nw = wn * 64;
    const int l31 = l & 31;
    const int hi16 = (l >> 5) << 4;
    const int swzA = (l & 7) << 4;
    const int swzA8 = (l & 4) << 2;                       // tap-8: ((l>>2)&1)<<4

    // ---- A row base offsets (bytes within F region of a buffer) ----
    int rowterm[3];
#pragma unroll
    for (int f = 0; f < 3; f++)
        rowterm[f] = (wm * 96 + f * 32 + l31) * 288;

    // ---- B swizzled offsets (bytes within buffer, c-invariant) ----
    int addrB[9][2];
#pragma unroll
    for (int t = 0; t < 9; t++) {
        int r = t / 3, dx = t % 3 - 1;
#pragma unroll
        for (int g = 0; g < 2; g++) {
            int colw = (nw + g * 32 + l31 + dx) & 255;
            addrB[t][g] = XOFF + r * 8192 + ((colw * 32 + hi16) ^ ((colw & 7) << 4));
        }
    }

    floatx16 acc[3][2];
#pragma unroll
    for (int f = 0; f < 3; f++)
#pragma unroll
        for (int g = 0; g < 2; g++)
#pragma unroll
            for (int r = 0; r < 16; r++) acc[f][g][r] = 0.f;

    // ---- async stage of channel c into buffer bsel (78 x 1KB segments) ----
    auto stage = [&](int c, int bsel) {
        char* base = lds + bsel * BUFB;
        for (int s = w; s < 78; s += 8) {
            const unsigned short* g;
            char* lb;
            if (s < 54) {                                  // F: 55296 B linear
                g = Fg + (size_t)c * FG_C + s * 512;
                lb = base + s * 1024;
            } else {                                       // X: 3 rows x 8192 B
                int j = s - 54;
                int r = j >> 3, p = j & 7;
                int yr = (y + r + 255) & 255;
                g = Xb + ((size_t)yr * 12 + c) * XB_CH + p * 512;
                lb = base + XOFF + r * 8192 + p * 1024;
            }
            __builtin_amdgcn_global_load_lds(
                (const __attribute__((address_space(1))) unsigned int*)(g + l * 8),
                (__attribute__((address_space(3))) unsigned int*)lb, 16, 0, 0);
        }
    };

    stage(0, 0);
    __syncthreads();

    int cur = 0;
    for (int c = 0; c < 12; c++) {
        if (c < 11) stage(c + 1, cur ^ 1);                 // overlaps compute below
        const char* fb = lds + cur * BUFB;
#pragma unroll
        for (int t = 0; t < 9; t++) {
            short8 A[3], B[2];
            int kterm = (t < 8) ? ((t * 32 + hi16) ^ swzA)
                                : ((256 + hi16) ^ swzA8);
#pragma unroll
            for (int f = 0; f < 3; f++)
                A[f] = *(const short8*)(fb + rowterm[f] + kterm);
#pragma unroll
            for (int g = 0; g < 2; g++)
                B[g] = *(const short8*)(fb + addrB[t][g]);
#pragma unroll
            for (int f = 0; f < 3; f++)
#pragma unroll
                for (int g = 0; g < 2; g++)
                    acc[f][g] = __builtin_amdgcn_mfma_f32_32x32x16_bf16(A[f], B[g], acc[f][g], 0, 0, 0);
        }
        __syncthreads();                                   // drains stage(c+1)
        cur ^= 1;
    }

    // ------------------------------------------------------- epilogue ----
    // co = wm*96 + f*32 + (r&3) + 8*(r>>2) + 4*(lane>>5); col = nw+g*32+l31.
    const int hi4 = (l >> 5) * 4;
#pragma unroll
    for (int f = 0; f < 3; f++) {
#pragma unroll
        for (int g = 0; g < 2; g++) {
            int col = nw + g * 32 + l31;
#pragma unroll
            for (int rr = 0; rr < 4; rr++) {
                int co0 = wm * 96 + f * 32 + hi4 + 8 * rr;  // multiple of 4
                if (co0 < 64) {
#pragma unroll
                    for (int q = 0; q < 4; q++)
                        out[(size_t)(co0 + q) * NPIX + y * NN + col] =
                            acc[f][g][rr * 4 + q] + b0[co0 + q];
                } else {
#pragma unroll
                    for (int q = 0; q < 4; q += 2) {
                        int c1 = co0 + q - 64;
                        float2 v = make_float2(acc[f][g][rr * 4 + q] + meanb[c1],
                                               acc[f][g][rr * 4 + q + 1] + meanb[c1 + 1]);
                        *((float2*)(out + OUT1_OFF) + ((size_t)(c1 >> 1) * NPIX + y * NN + col)) = v;
                    }
                }
            }
        }
    }
}

// --------------------------------------------------------------- launch ----
extern "C" void kernel_launch(void* const* d_in, const int* in_sizes, int n_in,
                              void* d_out, int out_size, void* d_ws, size_t ws_size,
                              hipStream_t stream) {
    const float* x0   = (const float*)d_in[0];
    const float* x1   = (const float*)d_in[1];
    const float* fil0 = (const float*)d_in[2];
    const float* fil1 = (const float*)d_in[3];
    const float* fil2 = (const float*)d_in[4];
    const float* w00  = (const float*)d_in[5];
    const float* w01  = (const float*)d_in[6];
    const float* w10  = (const float*)d_in[7];
    const float* w11  = (const float*)d_in[8];
    const float* b0   = (const float*)d_in[9];
    const float* b1   = (const float*)d_in[10];

    unsigned short* Xb = (unsigned short*)d_ws;                       // 25,165,824 B
    unsigned short* Fg = (unsigned short*)((char*)d_ws + 25165824);   //    663,552 B
    float* partial     = (float*)((char*)d_ws + 25829376);            //    196,608 B
    float* meanb       = (float*)((char*)d_ws + 26025984);            //        512 B
    float* out = (float*)d_out;

    prep_kernel<<<dim3(64, 12), 256, 0, stream>>>(x0, x1, Xb, partial);

    synth_kernel<<<(12 * 192 * 144 + 255) / 256, 256, 0, stream>>>(
        fil0, fil1, fil2, w00, w01, w10, w11, Fg);

    meanbx_kernel<<<128, 256, 0, stream>>>(Fg, partial, b1, meanb);

    conv_kernel<<<dim3(256), 512, 0, stream>>>(Xb, Fg, b0, meanb, out);
}

// Round 5
// 173.849 us; speedup vs baseline: 1.0754x; 1.0024x over previous
//
#include <hip/hip_runtime.h>
#include <hip/hip_bf16.h>
#include <string.h>

// ConvContract via bf16 MFMA implicit GEMM, 32x32x16, occupancy-tuned.
// prep:   Xb[y][c][col][cl] bf16, XOR-swizzled within each 8KB (y,c) row:
//         byte ^= (col&7)<<4. Row sums -> partial. y XCD-chunked.
// synth:  Fg[c][co][144] bf16 (9 taps x 16 cl), pre-swizzled per 8-granule
//         aligned block: taps 0-7: g ^= co&7; tap 8: g ^= (co>>2)&1.
// meanx:  mX[cc] = mean_y partial[cc][y]  (192 blocks, coalesced).
// meanbx: meanb[c1] = b1 * sum_k F[64+c1][k] * mX (torus identity).
// conv:   C[192][65536] = sum_c F*X via mfma_f32_32x32x16_bf16.
//         grid (256 y, 3 mtile of 64 rows) = 768 blocks of 256 thr (4 waves,
//         wave tile 64x64) -> 3 blocks/CU, 3 waves/SIMD (TLP covers LDS
//         latency; R0-validated inter-block overlap hides staging).
//         Single 43008B LDS buffer, stage -> barrier -> compute -> barrier.

#define NN 256
#define NPIX 65536
#define OUT1_OFF 4194304
#define XB_CH 4096        // shorts per (y,c) row: 256 cols * 16 cl
#define FTILE 18432       // F bytes per block-channel: 64 rows * 288
#define XOFF2 18432       // X offset within LDS buffer
#define CBUF 43008        // FTILE + 24576

typedef __attribute__((ext_vector_type(8))) short short8;
typedef __attribute__((ext_vector_type(16))) float floatx16;

__device__ __forceinline__ unsigned short f2b(float x) {
    unsigned int u; memcpy(&u, &x, 4);
    return (unsigned short)((u + 0x7FFFu + ((u >> 16) & 1u)) >> 16);   // RTNE
}
__device__ __forceinline__ float b2f16(unsigned short u) {
    unsigned int v = ((unsigned int)u) << 16; float f; memcpy(&f, &v, 4); return f;
}
__device__ __forceinline__ unsigned int pack2(float a, float b) {
    return (unsigned int)f2b(a) | ((unsigned int)f2b(b) << 16);
}

// ----------------------------------------------------------------- prep ----
// grid (64 ygroup, 12 c), block 256 = 4 waves (wave -> y), lane tx -> cols 4tx..4tx+3.
// ygroup XCD-chunked: XCD k handles y in [32k, 32k+32) — matches conv.
__global__ __launch_bounds__(256) void prep_kernel(const float* __restrict__ x0,
                                                   const float* __restrict__ x1,
                                                   unsigned short* __restrict__ Xb,
                                                   float* __restrict__ partial) {
    const int t = threadIdx.x;
    const int w = t >> 6, tx = t & 63;
    const int bxs = blockIdx.x;
    const int yg = ((bxs & 7) << 3) | (bxs >> 3);     // XCD-chunked ygroup
    const int y = yg * 4 + w;
    const int c = blockIdx.y;
    const int col0 = tx * 4;

    unsigned int u[4][8];
    float sum[16];
    if (c < 4) {
        #pragma unroll
        for (int j = 0; j < 8; j++) {
            const float4 a = *(const float4*)(x0 + (size_t)(16 * c + 2 * j) * NPIX + y * NN + col0);
            const float4 b = *(const float4*)(x0 + (size_t)(16 * c + 2 * j + 1) * NPIX + y * NN + col0);
            u[0][j] = pack2(a.x, b.x);
            u[1][j] = pack2(a.y, b.y);
            u[2][j] = pack2(a.z, b.z);
            u[3][j] = pack2(a.w, b.w);
            sum[2 * j]     = a.x + a.y + a.z + a.w;
            sum[2 * j + 1] = b.x + b.y + b.z + b.w;
        }
    } else {
        #pragma unroll
        for (int j = 0; j < 8; j++) {
            int i = 8 * (c - 4) + j;
            const float* base = x1 + ((size_t)(i * 256 + y) * 256 + col0) * 2;
            const float4 p0 = *(const float4*)(base);
            const float4 p1 = *(const float4*)(base + 4);
            u[0][j] = pack2(p0.x, p0.y);
            u[1][j] = pack2(p0.z, p0.w);
            u[2][j] = pack2(p1.x, p1.y);
            u[3][j] = pack2(p1.z, p1.w);
            sum[2 * j]     = p0.x + p0.z + p1.x + p1.z;
            sum[2 * j + 1] = p0.y + p0.w + p1.y + p1.w;
        }
    }
    // swizzled store: within the 8KB (y,c) row, byte ^= (col&7)<<4
    char* rowp = (char*)(Xb + ((size_t)y * 12 + c) * XB_CH);
    #pragma unroll
    for (int cc = 0; cc < 4; cc++) {
        int col = col0 + cc;
        int sw = (col & 7) << 4;
        *(uint4*)(rowp + ((col * 32)      ^ sw)) = make_uint4(u[cc][0], u[cc][1], u[cc][2], u[cc][3]);
        *(uint4*)(rowp + ((col * 32 + 16) ^ sw)) = make_uint4(u[cc][4], u[cc][5], u[cc][6], u[cc][7]);
    }
    #pragma unroll
    for (int cl = 0; cl < 16; cl++)
        #pragma unroll
        for (int d = 1; d < 64; d <<= 1) sum[cl] += __shfl_xor(sum[cl], d, 64);
    if (tx < 16) partial[(c * 16 + tx) * 256 + y] = sum[tx];
}

// ---------------------------------------------------------------- synth ----
// Fg[c][co][off_sw]: taps 0-7: off = ((tap*16+(cl&8)) ^ ((co&7)<<3)) + (cl&7);
// tap 8: off = ((128+(cl&8)) ^ (((co>>2)&1)<<3)) + (cl&7)  (closure-safe).
__global__ void synth_kernel(const float* __restrict__ fil0, const float* __restrict__ fil1,
                             const float* __restrict__ fil2,
                             const float* __restrict__ w00, const float* __restrict__ w01,
                             const float* __restrict__ w10, const float* __restrict__ w11,
                             unsigned short* __restrict__ Fg) {
    int idx = blockIdx.x * 256 + threadIdx.x;
    if (idx >= 12 * 192 * 144) return;
    int kpos = idx % 144;
    int co   = (idx / 144) % 192;
    int c    = idx / (144 * 192);
    int tap = kpos >> 4, cl = kpos & 15;
    float s = 0.0f;
    {
        int cin = c * 16 + cl;
        if (co < 64) {
            if (cin < 64) {
                for (int k = 0; k < 3; k++)
                    s += w00[(co * 64 + cin) * 3 + k] * fil0[k * 9 + tap];
            } else {
                int i = (cin - 64) >> 1, t = (cin - 64) & 1;
                for (int k = 0; k < 6; k++)
                    s += w10[(co * 64 + i) * 6 + k] * fil1[(k * 9 + tap) * 2 + t];
            }
        } else {
            int o = (co - 64) >> 1, u = (co - 64) & 1;
            if (cin < 64) {
                for (int k = 0; k < 6; k++)
                    s += w01[(o * 64 + cin) * 6 + k] * fil1[(k * 9 + tap) * 2 + u];
            } else {
                int i = (cin - 64) >> 1, t = (cin - 64) & 1;
                for (int k = 0; k < 12; k++)
                    s += w11[(o * 64 + i) * 12 + k] * fil2[((k * 9 + tap) * 2 + t) * 2 + u];
            }
        }
    }
    int swz = (tap < 8) ? ((co & 7) << 3) : (((co >> 2) & 1) << 3);
    int off = ((tap * 16 + (cl & 8)) ^ swz) + (cl & 7);
    Fg[((size_t)c * 192 + co) * 144 + off] = f2b(s);
}

// ---------------------------------------------------------------- meanx ----
// grid 192 (cc), block 64: mX[cc] = sum_y partial[cc][y] / 65536, coalesced.
__global__ void meanx_kernel(const float* __restrict__ partial, float* __restrict__ mXg) {
    const int cc = blockIdx.x;
    const int l = threadIdx.x;
    float4 v = ((const float4*)(partial + (size_t)cc * 256))[l];
    float s = v.x + v.y + v.z + v.w;
#pragma unroll
    for (int d = 1; d < 64; d <<= 1) s += __shfl_xor(s, d, 64);
    if (l == 0) mXg[cc] = s * (1.0f / 65536.0f);
}

// --------------------------------------------------------------- meanbx ----
// grid 128 (c1), block 256: meanb[c1] = b1[c1>>1] * sum F[64+c1][k] mX[cin(k)].
__global__ void meanbx_kernel(const unsigned short* __restrict__ Fg,
                              const float* __restrict__ mXg,
                              const float* __restrict__ b1, float* __restrict__ meanb) {
    __shared__ float mX[192];
    __shared__ float rd[4];
    const int c1 = blockIdx.x;
    const int t = threadIdx.x;
    if (t < 192) mX[t] = mXg[t];
    __syncthreads();
    float s = 0.0f;
    for (int e = t; e < 1728; e += 256) {
        int c = e / 144, r = e - c * 144;
        int tap = r >> 4, cl = r & 15;
        int swz = (tap < 8) ? ((c1 & 7) << 3) : (((c1 >> 2) & 1) << 3);
        int off = ((tap * 16 + (cl & 8)) ^ swz) + (cl & 7);
        s += b2f16(Fg[((size_t)c * 192 + 64 + c1) * 144 + off]) * mX[c * 16 + cl];
    }
#pragma unroll
    for (int d = 1; d < 64; d <<= 1) s += __shfl_xor(s, d, 64);
    if ((t & 63) == 0) rd[t >> 6] = s;
    __syncthreads();
    if (t == 0) meanb[c1] = (rd[0] + rd[1] + rd[2] + rd[3]) * b1[c1 >> 1];
}

// ----------------------------------------------------------------- conv ----
// grid (256 y, 3 mtile), block 256 = 4 waves (wave -> wn); wave tile 64M x 64N.
// mfma_f32_32x32x16_bf16: per tap, A 2 frags (64 rows), B 2 frags (64 cols),
// 4 MFMA. A/B lane map: row/col = lane&31, k = (lane>>5)*8 + j. C/D:
// col = lane&31, row = (reg&3)+8*(reg>>2)+4*(lane>>5).
__global__ __launch_bounds__(256, 3) void conv_kernel(
    const unsigned short* __restrict__ Xb, const unsigned short* __restrict__ Fg,
    const float* __restrict__ b0, const float* __restrict__ meanb,
    float* __restrict__ out) {

    __shared__ __align__(16) char lds[CBUF];              // 43008 B -> 3 blocks/CU

    const int tid = threadIdx.x;
    const int bx = blockIdx.x;
    const int y = ((bx & 7) << 5) | (bx >> 3);            // XCD-chunked y
    const int m0 = blockIdx.y * 64;
    const int l = tid & 63, w = tid >> 6;                  // w = wn
    const int nw = w * 64;
    const int l31 = l & 31;
    const int hi16 = (l >> 5) << 4;
    const int swzA = (l & 7) << 4;
    const int swzA8 = (l & 4) << 2;                        // tap-8 closure swz

    // ---- A row base offsets (bytes within F region) ----
    int rowterm[2];
#pragma unroll
    for (int f = 0; f < 2; f++)
        rowterm[f] = (f * 32 + l31) * 288;

    // ---- B swizzled offsets (bytes within buffer, c-invariant) ----
    int addrB[9][2];
#pragma unroll
    for (int t = 0; t < 9; t++) {
        int r = t / 3, dx = t % 3 - 1;
#pragma unroll
        for (int g = 0; g < 2; g++) {
            int colw = (nw + g * 32 + l31 + dx) & 255;
            addrB[t][g] = XOFF2 + r * 8192 + ((colw * 32 + hi16) ^ ((colw & 7) << 4));
        }
    }

    floatx16 acc[2][2];
#pragma unroll
    for (int f = 0; f < 2; f++)
#pragma unroll
        for (int g = 0; g < 2; g++)
#pragma unroll
            for (int r = 0; r < 16; r++) acc[f][g][r] = 0.f;

    for (int c = 0; c < 12; c++) {
        // ---- stage channel c: F 18 segs + X 24 segs, 1KB each ----
        for (int s = w; s < 42; s += 4) {
            const unsigned short* g;
            char* lb;
            if (s < 18) {                                  // F rows [m0,m0+64)
                g = Fg + ((size_t)c * 192 + m0) * 144 + s * 512;
                lb = lds + s * 1024;
            } else {                                       // X: 3 rows x 8192 B
                int j = s - 18;
                int r = j >> 3, p = j & 7;
                int yr = (y + r + 255) & 255;
                g = Xb + ((size_t)yr * 12 + c) * XB_CH + p * 512;
                lb = lds + XOFF2 + r * 8192 + p * 1024;
            }
            __builtin_amdgcn_global_load_lds(
                (const __attribute__((address_space(1))) unsigned int*)(g + l * 8),
                (__attribute__((address_space(3))) unsigned int*)lb, 16, 0, 0);
        }
        __syncthreads();                                   // stage complete

        // ---- compute: 9 taps x (2 A x 2 B) MFMA ----
#pragma unroll
        for (int t = 0; t < 9; t++) {
            short8 A[2], B[2];
            int kterm = (t < 8) ? ((t * 32 + hi16) ^ swzA)
                                : ((256 + hi16) ^ swzA8);
#pragma unroll
            for (int f = 0; f < 2; f++)
                A[f] = *(const short8*)(lds + rowterm[f] + kterm);
#pragma unroll
            for (int g = 0; g < 2; g++)
                B[g] = *(const short8*)(lds + addrB[t][g]);
#pragma unroll
            for (int f = 0; f < 2; f++)
#pragma unroll
                for (int g = 0; g < 2; g++)
                    acc[f][g] = __builtin_amdgcn_mfma_f32_32x32x16_bf16(A[f], B[g], acc[f][g], 0, 0, 0);
        }
        __syncthreads();                                   // before overwrite
    }

    // ------------------------------------------------------- epilogue ----
    const int hi4 = (l >> 5) * 4;
#pragma unroll
    for (int f = 0; f < 2; f++) {
#pragma unroll
        for (int g = 0; g < 2; g++) {
            int col = nw + g * 32 + l31;
#pragma unroll
            for (int rr = 0; rr < 4; rr++) {
                int co0 = m0 + f * 32 + hi4 + 8 * rr;      // multiple of 4
                if (co0 < 64) {
#pragma unroll
                    for (int q = 0; q < 4; q++)
                        out[(size_t)(co0 + q) * NPIX + y * NN + col] =
                            acc[f][g][rr * 4 + q] + b0[co0 + q];
                } else {
#pragma unroll
                    for (int q = 0; q < 4; q += 2) {
                        int c1 = co0 + q - 64;
                        float2 v = make_float2(acc[f][g][rr * 4 + q] + meanb[c1],
                                               acc[f][g][rr * 4 + q + 1] + meanb[c1 + 1]);
                        *((float2*)(out + OUT1_OFF) + ((size_t)(c1 >> 1) * NPIX + y * NN + col)) = v;
                    }
                }
            }
        }
    }
}

// --------------------------------------------------------------- launch ----
extern "C" void kernel_launch(void* const* d_in, const int* in_sizes, int n_in,
                              void* d_out, int out_size, void* d_ws, size_t ws_size,
                              hipStream_t stream) {
    const float* x0   = (const float*)d_in[0];
    const float* x1   = (const float*)d_in[1];
    const float* fil0 = (const float*)d_in[2];
    const float* fil1 = (const float*)d_in[3];
    const float* fil2 = (const float*)d_in[4];
    const float* w00  = (const float*)d_in[5];
    const float* w01  = (const float*)d_in[6];
    const float* w10  = (const float*)d_in[7];
    const float* w11  = (const float*)d_in[8];
    const float* b0   = (const float*)d_in[9];
    const float* b1   = (const float*)d_in[10];

    unsigned short* Xb = (unsigned short*)d_ws;                       // 25,165,824 B
    unsigned short* Fg = (unsigned short*)((char*)d_ws + 25165824);   //    663,552 B
    float* partial     = (float*)((char*)d_ws + 25829376);            //    196,608 B
    float* meanb       = (float*)((char*)d_ws + 26025984);            //        512 B
    float* mXg         = (float*)((char*)d_ws + 26026496);            //        768 B
    float* out = (float*)d_out;

    prep_kernel<<<dim3(64, 12), 256, 0, stream>>>(x0, x1, Xb, partial);

    synth_kernel<<<(12 * 192 * 144 + 255) / 256, 256, 0, stream>>>(
        fil0, fil1, fil2, w00, w01, w10, w11, Fg);

    meanx_kernel<<<192, 64, 0, stream>>>(partial, mXg);

    meanbx_kernel<<<128, 256, 0, stream>>>(Fg, mXg, b1, meanb);

    conv_kernel<<<dim3(256, 3), 256, 0, stream>>>(Xb, Fg, b0, meanb, out);
}

// Round 6
// 166.236 us; speedup vs baseline: 1.1246x; 1.0458x over previous
//
#include <hip/hip_runtime.h>
#include <hip/hip_bf16.h>
#include <string.h>

// ConvContract via bf16 MFMA implicit GEMM (round-0 proven conv structure +
// meanx/meanbx split + XCD-chunked y + prep/synth fusion).
// prep_synth: (fused, block-branch)
//   prep part:  Xb[y][c][col][cl] = bf16(X[cin][y][x]) linear; partial row sums.
//               y-groups XCD-chunked to match conv's reader XCD.
//   synth part: Fb[c][co][kpos] bf16, kpos = tap*16+cl (tap 9 = zero), FS=160.
// meanx:  mX[cc] = mean_y partial[cc][y]  (192 blocks, coalesced).
// meanbx: meanb[c1] = b1 * sum_k F[64+c1][k] * mX  (torus identity).
// conv:   C[192][65536] = sum_k F*X via MFMA 16x16x32; grid (256 y, 2 mtile),
//         block 512 = 8 waves; 55296B LDS, stage -> sync -> compute -> sync.
//         2 blocks/CU, 16 waves/CU (TLP hides stage latency — R0-validated,
//         88% LDS-pipe busy = at its structural wall).

#define NN 256
#define NPIX 65536
#define OUT1_OFF 4194304
#define FS 160                 // F row stride (10 taps x 16 cl; tap 9 zero)

typedef __attribute__((ext_vector_type(8))) short short8;
typedef __attribute__((ext_vector_type(4))) float floatx4;

__device__ __forceinline__ unsigned short f2b(float x) {
    unsigned int u; memcpy(&u, &x, 4);
    return (unsigned short)((u + 0x7FFFu + ((u >> 16) & 1u)) >> 16);   // RTNE
}
__device__ __forceinline__ float b2f16(unsigned short u) {
    unsigned int v = ((unsigned int)u) << 16; float f; memcpy(&f, &v, 4); return f;
}
__device__ __forceinline__ unsigned int pack2(float a, float b) {
    return (unsigned int)f2b(a) | ((unsigned int)f2b(b) << 16);
}

// ----------------------------------------------------- prep + synth ----
// grid 2208 blocks of 256:
//   blocks [0,768):   prep. c = bid>>6, ygroup = XCD-chunk(bid&63), wave -> y.
//   blocks [768,2208): synth. idx = (bid-768)*256 + tid over 12*192*160.
__global__ __launch_bounds__(256) void prep_synth_kernel(
    const float* __restrict__ x0, const float* __restrict__ x1,
    const float* __restrict__ fil0, const float* __restrict__ fil1,
    const float* __restrict__ fil2,
    const float* __restrict__ w00, const float* __restrict__ w01,
    const float* __restrict__ w10, const float* __restrict__ w11,
    unsigned short* __restrict__ Xb, float* __restrict__ partial,
    unsigned short* __restrict__ Fb) {

    const int bid = blockIdx.x;
    if (bid < 768) {
        // ------------------------------------------------------ prep ----
        const int t = threadIdx.x;
        const int w = t >> 6, tx = t & 63;
        const int bxs = bid & 63;
        const int c = bid >> 6;
        const int yg = ((bxs & 7) << 3) | (bxs >> 3);   // XCD-chunked ygroup
        const int y = yg * 4 + w;
        const int col0 = tx * 4;

        unsigned int u[4][8];
        float sum[16];
        if (c < 4) {
            #pragma unroll
            for (int j = 0; j < 8; j++) {
                const float4 a = *(const float4*)(x0 + (size_t)(16 * c + 2 * j) * NPIX + y * NN + col0);
                const float4 b = *(const float4*)(x0 + (size_t)(16 * c + 2 * j + 1) * NPIX + y * NN + col0);
                u[0][j] = pack2(a.x, b.x);
                u[1][j] = pack2(a.y, b.y);
                u[2][j] = pack2(a.z, b.z);
                u[3][j] = pack2(a.w, b.w);
                sum[2 * j]     = a.x + a.y + a.z + a.w;
                sum[2 * j + 1] = b.x + b.y + b.z + b.w;
            }
        } else {
            #pragma unroll
            for (int j = 0; j < 8; j++) {
                int i = 8 * (c - 4) + j;
                const float* base = x1 + ((size_t)(i * 256 + y) * 256 + col0) * 2;
                const float4 p0 = *(const float4*)(base);
                const float4 p1 = *(const float4*)(base + 4);
                u[0][j] = pack2(p0.x, p0.y);
                u[1][j] = pack2(p0.z, p0.w);
                u[2][j] = pack2(p1.x, p1.y);
                u[3][j] = pack2(p1.z, p1.w);
                sum[2 * j]     = p0.x + p0.z + p1.x + p1.z;
                sum[2 * j + 1] = p0.y + p0.w + p1.y + p1.w;
            }
        }
        uint4* dst = (uint4*)(Xb + (((size_t)y * 12 + c) * 256 + col0) * 16);
        #pragma unroll
        for (int cc = 0; cc < 4; cc++) {
            dst[cc * 2]     = make_uint4(u[cc][0], u[cc][1], u[cc][2], u[cc][3]);
            dst[cc * 2 + 1] = make_uint4(u[cc][4], u[cc][5], u[cc][6], u[cc][7]);
        }
        #pragma unroll
        for (int cl = 0; cl < 16; cl++)
            #pragma unroll
            for (int d = 1; d < 64; d <<= 1) sum[cl] += __shfl_xor(sum[cl], d, 64);
        if (tx < 16) partial[(c * 16 + tx) * 256 + y] = sum[tx];
    } else {
        // ----------------------------------------------------- synth ----
        int idx = (bid - 768) * 256 + threadIdx.x;
        if (idx >= 12 * 192 * FS) return;
        int kpos = idx % FS;
        int co   = (idx / FS) % 192;
        int c    = idx / (FS * 192);
        int tap = kpos >> 4, cl = kpos & 15;
        float s = 0.0f;
        if (tap < 9) {
            int cin = c * 16 + cl;
            if (co < 64) {
                if (cin < 64) {
                    for (int k = 0; k < 3; k++)
                        s += w00[(co * 64 + cin) * 3 + k] * fil0[k * 9 + tap];
                } else {
                    int i = (cin - 64) >> 1, t = (cin - 64) & 1;
                    for (int k = 0; k < 6; k++)
                        s += w10[(co * 64 + i) * 6 + k] * fil1[(k * 9 + tap) * 2 + t];
                }
            } else {
                int o = (co - 64) >> 1, u = (co - 64) & 1;
                if (cin < 64) {
                    for (int k = 0; k < 6; k++)
                        s += w01[(o * 64 + cin) * 6 + k] * fil1[(k * 9 + tap) * 2 + u];
                } else {
                    int i = (cin - 64) >> 1, t = (cin - 64) & 1;
                    for (int k = 0; k < 12; k++)
                        s += w11[(o * 64 + i) * 12 + k] * fil2[((k * 9 + tap) * 2 + t) * 2 + u];
                }
            }
        }
        Fb[idx] = f2b(s);
    }
}

// ---------------------------------------------------------------- meanx ----
// grid 192 (cc), block 64: mX[cc] = sum_y partial[cc][y] / 65536, coalesced.
__global__ void meanx_kernel(const float* __restrict__ partial, float* __restrict__ mXg) {
    const int cc = blockIdx.x;
    const int l = threadIdx.x;
    float4 v = ((const float4*)(partial + (size_t)cc * 256))[l];
    float s = v.x + v.y + v.z + v.w;
#pragma unroll
    for (int d = 1; d < 64; d <<= 1) s += __shfl_xor(s, d, 64);
    if (l == 0) mXg[cc] = s * (1.0f / 65536.0f);
}

// --------------------------------------------------------------- meanbx ----
// grid 128 (c1), block 256: meanb[c1] = b1[c1>>1] * sum F[64+c1][k] mX[cin(k)].
__global__ void meanbx_kernel(const unsigned short* __restrict__ Fb,
                              const float* __restrict__ mXg,
                              const float* __restrict__ b1, float* __restrict__ meanb) {
    __shared__ float mX[192];
    __shared__ float rd[4];
    const int c1 = blockIdx.x;
    const int t = threadIdx.x;
    if (t < 192) mX[t] = mXg[t];
    __syncthreads();
    float s = 0.0f;
    for (int e = t; e < 1728; e += 256) {
        int c = e / 144, r = e - c * 144;
        int tap = r >> 4, cl = r & 15;
        s += b2f16(Fb[((size_t)c * 192 + 64 + c1) * FS + tap * 16 + cl]) * mX[c * 16 + cl];
    }
#pragma unroll
    for (int d = 1; d < 64; d <<= 1) s += __shfl_xor(s, d, 64);
    if ((t & 63) == 0) rd[t >> 6] = s;
    __syncthreads();
    if (t == 0) meanb[c1] = (rd[0] + rd[1] + rd[2] + rd[3]) * b1[c1 >> 1];
}

// ----------------------------------------------------------------- conv ----
// grid (256 y, 2 mtile), block 512 = 8 waves (2 wm x 4 wn); wave tile 48M x 64N.
// (round-0 structure verbatim; y XCD-chunked to match prep's writer XCD)
__global__ __launch_bounds__(512, 4) void conv_kernel(
    const unsigned short* __restrict__ Xb, const unsigned short* __restrict__ Fb,
    const float* __restrict__ b0, const float* __restrict__ meanb,
    float* __restrict__ out) {

    __shared__ __align__(16) unsigned short Flds[96 * FS];      // 30720 B
    __shared__ __align__(16) unsigned short Xlds[3 * 256 * 16]; // 24576 B

    const int tid = threadIdx.x;
    const int bx = blockIdx.x;
    const int y = ((bx & 7) << 5) | (bx >> 3);            // XCD-chunked y
    const int m0 = blockIdx.y * 96;
    const int l = tid & 63, w = tid >> 6;
    const int wm = w >> 2, wn = w & 3;
    const int mw = wm * 48, nw = wn * 64;
    const int ln = l & 15, quad = l >> 4;

    int baseA[3];
#pragma unroll
    for (int f = 0; f < 3; f++) baseA[f] = (mw + f * 16 + ln) * FS + quad * 8;
    int cb[4];
#pragma unroll
    for (int g = 0; g < 4; g++) cb[g] = nw + g * 16 + ln;
    int rofs[5], dxv[5];
#pragma unroll
    for (int ks = 0; ks < 5; ks++) {
        int tap = 2 * ks + (quad >> 1);
        int r, dx;
        if (tap > 8) { r = 0; dx = 0; }            // zero-pad tap: F=0, address harmless
        else { r = tap / 3; dx = tap - 3 * r - 1; }
        rofs[ks] = r * 4096 + (quad & 1) * 8;
        dxv[ks] = dx;
    }

    floatx4 acc[3][4];
#pragma unroll
    for (int f = 0; f < 3; f++)
#pragma unroll
        for (int g = 0; g < 4; g++) acc[f][g] = (floatx4){0.f, 0.f, 0.f, 0.f};

    for (int c = 0; c < 12; c++) {
        // ---- async stage: F (30 segs x 1KB) + X (24 segs x 1KB) ----
        const unsigned short* FbC = Fb + ((size_t)c * 192 + m0) * FS;
        for (int s = w; s < 54; s += 8) {
            const unsigned short* g;
            unsigned short* lb;
            if (s < 30) {
                g = FbC + s * 512;
                lb = Flds + s * 512;
            } else {
                int j = s - 30;
                int r = j >> 3, p = j & 7;
                int yr = (y + r + 255) & 255;
                g = Xb + (((size_t)yr * 12 + c) * 4096) + p * 512;
                lb = Xlds + r * 4096 + p * 512;
            }
            __builtin_amdgcn_global_load_lds(
                (const __attribute__((address_space(1))) unsigned int*)(g + l * 8),
                (__attribute__((address_space(3))) unsigned int*)lb, 16, 0, 0);
        }
        __syncthreads();

        // ---- compute: 5 K32 steps x (3 A x 4 B) ----
#pragma unroll
        for (int ks = 0; ks < 5; ks++) {
            short8 A[3], B[4];
#pragma unroll
            for (int f = 0; f < 3; f++)
                A[f] = *(const short8*)(Flds + baseA[f] + ks * 32);
#pragma unroll
            for (int g = 0; g < 4; g++) {
                int colw = (cb[g] + dxv[ks]) & 255;
                B[g] = *(const short8*)(Xlds + rofs[ks] + colw * 16);
            }
#pragma unroll
            for (int f = 0; f < 3; f++)
#pragma unroll
                for (int g = 0; g < 4; g++)
                    acc[f][g] = __builtin_amdgcn_mfma_f32_16x16x32_bf16(A[f], B[g], acc[f][g], 0, 0, 0);
        }
        __syncthreads();
    }

    // ------------------------------------------------------- epilogue ----
    // C/D layout: col = ln, row(within 16) = quad*4 + reg.
#pragma unroll
    for (int f = 0; f < 3; f++) {
        int cob = m0 + mw + f * 16 + quad * 4;
#pragma unroll
        for (int g = 0; g < 4; g++) {
            int col = nw + g * 16 + ln;
            if (cob < 64) {
#pragma unroll
                for (int reg = 0; reg < 4; reg++)
                    out[(size_t)(cob + reg) * NPIX + y * NN + col] = acc[f][g][reg] + b0[cob + reg];
            } else {
#pragma unroll
                for (int reg = 0; reg < 4; reg += 2) {
                    int c1 = cob + reg - 64;
                    int o = c1 >> 1;
                    float2 v = make_float2(acc[f][g][reg] + meanb[c1],
                                           acc[f][g][reg + 1] + meanb[c1 + 1]);
                    *((float2*)(out + OUT1_OFF) + ((size_t)o * NPIX + y * NN + col)) = v;
                }
            }
        }
    }
}

// --------------------------------------------------------------- launch ----
extern "C" void kernel_launch(void* const* d_in, const int* in_sizes, int n_in,
                              void* d_out, int out_size, void* d_ws, size_t ws_size,
                              hipStream_t stream) {
    const float* x0   = (const float*)d_in[0];
    const float* x1   = (const float*)d_in[1];
    const float* fil0 = (const float*)d_in[2];
    const float* fil1 = (const float*)d_in[3];
    const float* fil2 = (const float*)d_in[4];
    const float* w00  = (const float*)d_in[5];
    const float* w01  = (const float*)d_in[6];
    const float* w10  = (const float*)d_in[7];
    const float* w11  = (const float*)d_in[8];
    const float* b0   = (const float*)d_in[9];
    const float* b1   = (const float*)d_in[10];

    unsigned short* Xb = (unsigned short*)d_ws;                       // 25,165,824 B
    unsigned short* Fb = (unsigned short*)((char*)d_ws + 25165824);   //    737,280 B
    float* partial     = (float*)((char*)d_ws + 25903104);            //    196,608 B
    float* meanb       = (float*)((char*)d_ws + 26099712);            //        512 B
    float* mXg         = (float*)((char*)d_ws + 26100224);            //        768 B
    float* out = (float*)d_out;

    // prep: 768 blocks; synth: 1440 blocks (12*192*160 / 256)
    prep_synth_kernel<<<768 + 1440, 256, 0, stream>>>(
        x0, x1, fil0, fil1, fil2, w00, w01, w10, w11, Xb, partial, Fb);

    meanx_kernel<<<192, 64, 0, stream>>>(partial, mXg);

    meanbx_kernel<<<128, 256, 0, stream>>>(Fb, mXg, b1, meanb);

    conv_kernel<<<dim3(NN, 2), 512, 0, stream>>>(Xb, Fb, b0, meanb, out);
}